// Round 1
// baseline (803.511 us; speedup 1.0000x reference)
//
#include <hip/hip_runtime.h>
#include <stdint.h>

#define T_TOK 4096
#define H_DIM 1024
#define E_NUM 8
#define I_DIM 2048
#define CAP   9216   // max padded assignments: 8192 + 8*127 -> round up
#define LDK   72     // LDS row stride in ushorts (144B: 16B-aligned, breaks 32-bank pow2 stride)

typedef float f32x4 __attribute__((ext_vector_type(4)));
typedef __bf16 bf16x8 __attribute__((ext_vector_type(8)));

__device__ __forceinline__ unsigned short f2bf(float f) {
    union { float f; unsigned int u; } v; v.f = f;
    unsigned int u = v.u;
    return (unsigned short)((u + 0x7fffu + ((u >> 16) & 1u)) >> 16);  // RNE
}

// ---------- router: routes = x@Wr (fp32 exact), top2 + softmax, x -> bf16 ----------
__global__ __launch_bounds__(256)
void router_kernel(const float* __restrict__ x, const float* __restrict__ Wr,
                   unsigned short* __restrict__ xb, int* __restrict__ topidx,
                   float* __restrict__ topw, int* __restrict__ counts) {
    int t = blockIdx.x;
    int tid = threadIdx.x;
    const float* xrow = x + (size_t)t * H_DIM;
    float acc[E_NUM];
#pragma unroll
    for (int e = 0; e < E_NUM; e++) acc[e] = 0.f;
    for (int h = tid; h < H_DIM; h += 256) {
        float xv = xrow[h];
        xb[(size_t)t * H_DIM + h] = f2bf(xv);
        const float* wr = Wr + (size_t)h * E_NUM;
#pragma unroll
        for (int e = 0; e < E_NUM; e++) acc[e] += xv * wr[e];
    }
    __shared__ float red[256][E_NUM];
#pragma unroll
    for (int e = 0; e < E_NUM; e++) red[tid][e] = acc[e];
    __syncthreads();
    for (int s = 128; s > 0; s >>= 1) {
        if (tid < s) {
#pragma unroll
            for (int e = 0; e < E_NUM; e++) red[tid][e] += red[tid + s][e];
        }
        __syncthreads();
    }
    if (tid == 0) {
        float v0 = -1e30f; int i0 = 0;
        for (int e = 0; e < E_NUM; e++) { float v = red[0][e]; if (v > v0) { v0 = v; i0 = e; } }
        float v1 = -1e30f; int i1 = 1;
        for (int e = 0; e < E_NUM; e++) { if (e == i0) continue; float v = red[0][e]; if (v > v1) { v1 = v; i1 = e; } }
        float e1 = expf(v1 - v0);
        float s = 1.f + e1;
        topidx[t * 2 + 0] = i0; topidx[t * 2 + 1] = i1;
        topw[t * 2 + 0] = 1.f / s; topw[t * 2 + 1] = e1 / s;
        atomicAdd(&counts[i0], 1); atomicAdd(&counts[i1], 1);
    }
}

// ---------- offsets: pad each expert count to multiple of 128, exclusive scan ----------
__global__ void offsets_kernel(const int* __restrict__ counts, int* __restrict__ padded,
                               int* __restrict__ offs) {
    if (threadIdx.x == 0 && blockIdx.x == 0) {
        int off = 0;
        for (int e = 0; e < E_NUM; e++) {
            offs[e] = off;
            int p = (counts[e] + 127) & ~127;
            padded[e] = p;
            off += p;
        }
        offs[E_NUM] = off;
    }
}

// ---------- scatter assignments into per-expert lists ----------
__global__ __launch_bounds__(256)
void scatter_kernel(const int* __restrict__ topidx, const float* __restrict__ topw,
                    const int* __restrict__ offs, int* __restrict__ cursors,
                    int* __restrict__ list_tok, float* __restrict__ list_w) {
    int a = blockIdx.x * 256 + threadIdx.x;
    if (a >= T_TOK * 2) return;
    int e = topidx[a];
    int pos = atomicAdd(&cursors[e], 1);
    int slot = offs[e] + pos;
    list_tok[slot] = a >> 1;
    list_w[slot]   = topw[a];
}

// ---------- fill pad slots with token 0 / weight 0 (max 127 per expert) ----------
__global__ void pad_kernel(const int* __restrict__ counts, const int* __restrict__ padded,
                           const int* __restrict__ offs, int* __restrict__ list_tok,
                           float* __restrict__ list_w) {
    int e = blockIdx.x;
    int pos = counts[e] + (int)threadIdx.x;
    if (pos < padded[e]) {
        list_tok[offs[e] + pos] = 0;
        list_w[offs[e] + pos]   = 0.f;
    }
}

// ---------- tiled transpose + fp32->bf16: out[c][r] = bf16(in[r][c]), per expert ----------
__global__ __launch_bounds__(256)
void transpose_cvt(const float* __restrict__ in, unsigned short* __restrict__ out,
                   int R, int C) {
    __shared__ float tile[64][65];
    size_t mat = (size_t)R * C;
    const float* inp = in + (size_t)blockIdx.z * mat;
    unsigned short* outp = out + (size_t)blockIdx.z * mat;
    int c0 = blockIdx.x * 64, r0 = blockIdx.y * 64;
    int tx = threadIdx.x, ty = threadIdx.y;
#pragma unroll
    for (int j = 0; j < 64; j += 4)
        tile[ty + j][tx] = inp[(size_t)(r0 + ty + j) * C + (c0 + tx)];
    __syncthreads();
#pragma unroll
    for (int j = 0; j < 64; j += 4)
        outp[(size_t)(c0 + ty + j) * R + (r0 + tx)] = f2bf(tile[tx][ty + j]);
}

// ---------- fused gate/up GEMM + SwiGLU: h[slot][i] = silu(x@Wg)*(x@Wu), bf16 ----------
__global__ __launch_bounds__(256, 2)
void gemm_gateup(const unsigned short* __restrict__ xb, const unsigned short* __restrict__ wgT,
                 const unsigned short* __restrict__ wuT, const int* __restrict__ list_tok,
                 const int* __restrict__ padded, const int* __restrict__ offs,
                 unsigned short* __restrict__ hbuf) {
    int e = blockIdx.z, mt = blockIdx.x, nt = blockIdx.y;
    if (mt * 128 >= padded[e]) return;
    int base = offs[e] + mt * 128;

    __shared__ unsigned short As[128 * LDK];
    __shared__ unsigned short Bgs[128 * LDK];
    __shared__ unsigned short Bus[128 * LDK];
    __shared__ int toks[128];

    int tid = threadIdx.x;
    if (tid < 128) toks[tid] = list_tok[base + tid];
    __syncthreads();

    const unsigned short* wg = wgT + ((size_t)e * I_DIM + (size_t)nt * 128) * H_DIM;
    const unsigned short* wu = wuT + ((size_t)e * I_DIM + (size_t)nt * 128) * H_DIM;

    f32x4 accg[4][4], accu[4][4];
    f32x4 z = {0.f, 0.f, 0.f, 0.f};
#pragma unroll
    for (int i = 0; i < 4; i++)
#pragma unroll
        for (int j = 0; j < 4; j++) { accg[i][j] = z; accu[i][j] = z; }

    int wv = tid >> 6, lane = tid & 63;
    int wm = (wv >> 1) * 64, wn = (wv & 1) * 64;
    int l16 = lane & 15, quad = lane >> 4;

    for (int kb = 0; kb < H_DIM; kb += 64) {
#pragma unroll
        for (int i = 0; i < 4; i++) {
            int c = tid + i * 256;           // 0..1023 chunk id
            int row = c >> 3, kc = (c & 7) * 8;
            *(uint4*)(&As[row * LDK + kc])  = *(const uint4*)(xb + (size_t)toks[row] * H_DIM + kb + kc);
            *(uint4*)(&Bgs[row * LDK + kc]) = *(const uint4*)(wg + (size_t)row * H_DIM + kb + kc);
            *(uint4*)(&Bus[row * LDK + kc]) = *(const uint4*)(wu + (size_t)row * H_DIM + kb + kc);
        }
        __syncthreads();
#pragma unroll
        for (int ks = 0; ks < 2; ks++) {
            bf16x8 af[4], bg[4], bu[4];
#pragma unroll
            for (int i = 0; i < 4; i++)
                af[i] = *(const bf16x8*)(&As[(wm + i * 16 + l16) * LDK + ks * 32 + quad * 8]);
#pragma unroll
            for (int j = 0; j < 4; j++) {
                bg[j] = *(const bf16x8*)(&Bgs[(wn + j * 16 + l16) * LDK + ks * 32 + quad * 8]);
                bu[j] = *(const bf16x8*)(&Bus[(wn + j * 16 + l16) * LDK + ks * 32 + quad * 8]);
            }
#pragma unroll
            for (int i = 0; i < 4; i++)
#pragma unroll
                for (int j = 0; j < 4; j++) {
                    accg[i][j] = __builtin_amdgcn_mfma_f32_16x16x32_bf16(af[i], bg[j], accg[i][j], 0, 0, 0);
                    accu[i][j] = __builtin_amdgcn_mfma_f32_16x16x32_bf16(af[i], bu[j], accu[i][j], 0, 0, 0);
                }
        }
        __syncthreads();
    }
#pragma unroll
    for (int i = 0; i < 4; i++) {
#pragma unroll
        for (int r = 0; r < 4; r++) {
            int row = wm + i * 16 + quad * 4 + r;                  // C/D: col=lane&15, row=quad*4+reg
            size_t hb = (size_t)(base + row) * I_DIM + (size_t)nt * 128 + wn;
#pragma unroll
            for (int j = 0; j < 4; j++) {
                float g = accg[i][j][r];
                float u = accu[i][j][r];
                float sig = 1.f / (1.f + __expf(-g));
                hbuf[hb + j * 16 + l16] = f2bf(g * sig * u);
            }
        }
    }
}

// ---------- down GEMM: out[tok] += w * (h @ Wd) via fp32 atomics ----------
__global__ __launch_bounds__(256, 2)
void gemm_down(const unsigned short* __restrict__ hbuf, const unsigned short* __restrict__ wdT,
               const int* __restrict__ list_tok, const float* __restrict__ list_w,
               const int* __restrict__ padded, const int* __restrict__ offs,
               float* __restrict__ out) {
    int e = blockIdx.z, mt = blockIdx.x, nt = blockIdx.y;
    if (mt * 128 >= padded[e]) return;
    int base = offs[e] + mt * 128;

    __shared__ unsigned short As[128 * LDK];
    __shared__ unsigned short Bs[128 * LDK];
    __shared__ int toks[128];
    __shared__ float wsh[128];

    int tid = threadIdx.x;
    if (tid < 128) { toks[tid] = list_tok[base + tid]; wsh[tid] = list_w[base + tid]; }
    __syncthreads();

    const unsigned short* wd = wdT + ((size_t)e * H_DIM + (size_t)nt * 128) * I_DIM;

    f32x4 acc[4][4];
    f32x4 z = {0.f, 0.f, 0.f, 0.f};
#pragma unroll
    for (int i = 0; i < 4; i++)
#pragma unroll
        for (int j = 0; j < 4; j++) acc[i][j] = z;

    int wv = tid >> 6, lane = tid & 63;
    int wm = (wv >> 1) * 64, wn = (wv & 1) * 64;
    int l16 = lane & 15, quad = lane >> 4;

    for (int kb = 0; kb < I_DIM; kb += 64) {
#pragma unroll
        for (int i = 0; i < 4; i++) {
            int c = tid + i * 256;
            int row = c >> 3, kc = (c & 7) * 8;
            *(uint4*)(&As[row * LDK + kc]) = *(const uint4*)(hbuf + (size_t)(base + row) * I_DIM + kb + kc);
            *(uint4*)(&Bs[row * LDK + kc]) = *(const uint4*)(wd + (size_t)row * I_DIM + kb + kc);
        }
        __syncthreads();
#pragma unroll
        for (int ks = 0; ks < 2; ks++) {
            bf16x8 af[4], bf[4];
#pragma unroll
            for (int i = 0; i < 4; i++)
                af[i] = *(const bf16x8*)(&As[(wm + i * 16 + l16) * LDK + ks * 32 + quad * 8]);
#pragma unroll
            for (int j = 0; j < 4; j++)
                bf[j] = *(const bf16x8*)(&Bs[(wn + j * 16 + l16) * LDK + ks * 32 + quad * 8]);
#pragma unroll
            for (int i = 0; i < 4; i++)
#pragma unroll
                for (int j = 0; j < 4; j++)
                    acc[i][j] = __builtin_amdgcn_mfma_f32_16x16x32_bf16(af[i], bf[j], acc[i][j], 0, 0, 0);
        }
        __syncthreads();
    }
#pragma unroll
    for (int i = 0; i < 4; i++) {
#pragma unroll
        for (int r = 0; r < 4; r++) {
            int row = wm + i * 16 + quad * 4 + r;
            float wgt = wsh[row];
            if (wgt != 0.f) {
                float* orow = out + (size_t)toks[row] * H_DIM + (size_t)nt * 128 + wn;
#pragma unroll
                for (int j = 0; j < 4; j++)
                    atomicAdd(&orow[j * 16 + l16], wgt * acc[i][j][r]);
            }
        }
    }
}

extern "C" void kernel_launch(void* const* d_in, const int* in_sizes, int n_in,
                              void* d_out, int out_size, void* d_ws, size_t ws_size,
                              hipStream_t stream) {
    const float* x  = (const float*)d_in[0];
    const float* Wr = (const float*)d_in[1];
    const float* Wg = (const float*)d_in[2];
    const float* Wu = (const float*)d_in[3];
    const float* Wd = (const float*)d_in[4];
    float* out = (float*)d_out;
    char* ws = (char*)d_ws;

    size_t off = 0;
    unsigned short* xb   = (unsigned short*)(ws + off); off += (size_t)T_TOK * H_DIM * 2;
    unsigned short* wgT  = (unsigned short*)(ws + off); off += (size_t)E_NUM * H_DIM * I_DIM * 2;
    unsigned short* wuT  = (unsigned short*)(ws + off); off += (size_t)E_NUM * H_DIM * I_DIM * 2;
    unsigned short* wdT  = (unsigned short*)(ws + off); off += (size_t)E_NUM * H_DIM * I_DIM * 2;
    unsigned short* hbuf = (unsigned short*)(ws + off); off += (size_t)CAP * I_DIM * 2;
    int*   topidx  = (int*)(ws + off);   off += (size_t)T_TOK * 2 * 4;
    float* topw    = (float*)(ws + off); off += (size_t)T_TOK * 2 * 4;
    int*   counts  = (int*)(ws + off);   off += 256;  // counts(8), cursors(8), padded(8), offs(9)
    int*   cursors = counts + 8;
    int*   padded  = counts + 16;
    int*   offs    = counts + 24;
    int*   list_tok = (int*)(ws + off);  off += (size_t)CAP * 4;
    float* list_w   = (float*)(ws + off); off += (size_t)CAP * 4;

    hipMemsetAsync(out, 0, (size_t)out_size * sizeof(float), stream);
    hipMemsetAsync(counts, 0, 64, stream);  // counts + cursors

    router_kernel<<<T_TOK, 256, 0, stream>>>(x, Wr, xb, topidx, topw, counts);
    transpose_cvt<<<dim3(I_DIM / 64, H_DIM / 64, E_NUM), dim3(64, 4), 0, stream>>>(Wg, wgT, H_DIM, I_DIM);
    transpose_cvt<<<dim3(I_DIM / 64, H_DIM / 64, E_NUM), dim3(64, 4), 0, stream>>>(Wu, wuT, H_DIM, I_DIM);
    transpose_cvt<<<dim3(H_DIM / 64, I_DIM / 64, E_NUM), dim3(64, 4), 0, stream>>>(Wd, wdT, I_DIM, H_DIM);
    offsets_kernel<<<1, 1, 0, stream>>>(counts, padded, offs);
    scatter_kernel<<<(T_TOK * 2) / 256, 256, 0, stream>>>(topidx, topw, offs, cursors, list_tok, list_w);
    pad_kernel<<<E_NUM, 128, 0, stream>>>(counts, padded, offs, list_tok, list_w);
    gemm_gateup<<<dim3(64, I_DIM / 128, E_NUM), 256, 0, stream>>>(xb, wgT, wuT, list_tok, padded, offs, hbuf);
    gemm_down<<<dim3(64, H_DIM / 128, E_NUM), 256, 0, stream>>>(hbuf, wdT, list_tok, list_w, padded, offs, out);
}

// Round 2
// 590.266 us; speedup vs baseline: 1.3613x; 1.3613x over previous
//
#include <hip/hip_runtime.h>
#include <stdint.h>

#define T_TOK 4096
#define H_DIM 1024
#define E_NUM 8
#define I_DIM 2048
#define CAP   9216   // max padded assignments: 8192 + 8*127 -> rounded up
#define MAXTILES 72  // CAP/128

typedef float f32x4 __attribute__((ext_vector_type(4)));
typedef __bf16 bf16x8 __attribute__((ext_vector_type(8)));

__device__ __forceinline__ unsigned short f2bf(float f) {
    union { float f; unsigned int u; } v; v.f = f;
    unsigned int u = v.u;
    return (unsigned short)((u + 0x7fffu + ((u >> 16) & 1u)) >> 16);  // RNE
}

// async global->LDS, 16B per lane. LDS dest = wave-uniform base + lane*16.
__device__ __forceinline__ void async16(const unsigned short* g, unsigned short* l) {
    __builtin_amdgcn_global_load_lds(
        (const __attribute__((address_space(1))) unsigned int*)g,
        (__attribute__((address_space(3))) unsigned int*)l,
        16, 0, 0);
}

// ---------- router: routes = x@Wr (fp32 exact), top2 + softmax, x -> bf16 ----------
__global__ __launch_bounds__(256)
void router_kernel(const float* __restrict__ x, const float* __restrict__ Wr,
                   unsigned short* __restrict__ xb, int* __restrict__ topidx,
                   float* __restrict__ topw, int* __restrict__ counts) {
    int t = blockIdx.x;
    int tid = threadIdx.x;
    const float* xrow = x + (size_t)t * H_DIM;
    float acc[E_NUM];
#pragma unroll
    for (int e = 0; e < E_NUM; e++) acc[e] = 0.f;
    for (int h = tid; h < H_DIM; h += 256) {
        float xv = xrow[h];
        xb[(size_t)t * H_DIM + h] = f2bf(xv);
        const float* wr = Wr + (size_t)h * E_NUM;
#pragma unroll
        for (int e = 0; e < E_NUM; e++) acc[e] += xv * wr[e];
    }
    __shared__ float red[256][E_NUM];
#pragma unroll
    for (int e = 0; e < E_NUM; e++) red[tid][e] = acc[e];
    __syncthreads();
    for (int s = 128; s > 0; s >>= 1) {
        if (tid < s) {
#pragma unroll
            for (int e = 0; e < E_NUM; e++) red[tid][e] += red[tid + s][e];
        }
        __syncthreads();
    }
    if (tid == 0) {
        float v0 = -1e30f; int i0 = 0;
        for (int e = 0; e < E_NUM; e++) { float v = red[0][e]; if (v > v0) { v0 = v; i0 = e; } }
        float v1 = -1e30f; int i1 = 1;
        for (int e = 0; e < E_NUM; e++) { if (e == i0) continue; float v = red[0][e]; if (v > v1) { v1 = v; i1 = e; } }
        float e1 = expf(v1 - v0);
        float s = 1.f + e1;
        topidx[t * 2 + 0] = i0; topidx[t * 2 + 1] = i1;
        topw[t * 2 + 0] = 1.f / s; topw[t * 2 + 1] = e1 / s;
        atomicAdd(&counts[i0], 1); atomicAdd(&counts[i1], 1);
    }
}

// ---------- offsets + flat tile map ----------
__global__ void offsets_kernel(const int* __restrict__ counts, int* __restrict__ padded,
                               int* __restrict__ offs, int* __restrict__ tile_e,
                               int* __restrict__ tile_base, int* __restrict__ ntiles) {
    if (threadIdx.x == 0 && blockIdx.x == 0) {
        int off = 0, t = 0;
        for (int e = 0; e < E_NUM; e++) {
            offs[e] = off;
            int p = (counts[e] + 127) & ~127;
            padded[e] = p;
            for (int m = 0; m < p; m += 128) { tile_e[t] = e; tile_base[t] = off + m; t++; }
            off += p;
        }
        offs[E_NUM] = off;
        ntiles[0] = t;
    }
}

// ---------- scatter assignments into per-expert lists ----------
__global__ __launch_bounds__(256)
void scatter_kernel(const int* __restrict__ topidx, const float* __restrict__ topw,
                    const int* __restrict__ offs, int* __restrict__ cursors,
                    int* __restrict__ list_tok, float* __restrict__ list_w) {
    int a = blockIdx.x * 256 + threadIdx.x;
    if (a >= T_TOK * 2) return;
    int e = topidx[a];
    int pos = atomicAdd(&cursors[e], 1);
    int slot = offs[e] + pos;
    list_tok[slot] = a >> 1;
    list_w[slot]   = topw[a];
}

// ---------- fill pad slots with token 0 / weight 0 ----------
__global__ void pad_kernel(const int* __restrict__ counts, const int* __restrict__ padded,
                           const int* __restrict__ offs, int* __restrict__ list_tok,
                           float* __restrict__ list_w) {
    int e = blockIdx.x;
    int pos = counts[e] + (int)threadIdx.x;
    if (pos < padded[e]) {
        list_tok[offs[e] + pos] = 0;
        list_w[offs[e] + pos]   = 0.f;
    }
}

// ---------- tiled transpose + fp32->bf16 ----------
__global__ __launch_bounds__(256)
void transpose_cvt(const float* __restrict__ in, unsigned short* __restrict__ out,
                   int R, int C) {
    __shared__ float tile[64][65];
    size_t mat = (size_t)R * C;
    const float* inp = in + (size_t)blockIdx.z * mat;
    unsigned short* outp = out + (size_t)blockIdx.z * mat;
    int c0 = blockIdx.x * 64, r0 = blockIdx.y * 64;
    int tx = threadIdx.x, ty = threadIdx.y;
#pragma unroll
    for (int j = 0; j < 64; j += 4)
        tile[ty + j][tx] = inp[(size_t)(r0 + ty + j) * C + (c0 + tx)];
    __syncthreads();
#pragma unroll
    for (int j = 0; j < 64; j += 4)
        outp[(size_t)(c0 + ty + j) * R + (r0 + tx)] = f2bf(tile[tx][ty + j]);
}

// ---------- fused gate/up GEMM + SwiGLU ----------
// LDS tiles unpadded (64 shorts = 128B row stride) for global_load_lds;
// XOR chunk swizzle: row R, k-chunk c stored at position c^(R&7) -> 2-way banks.
__global__ __launch_bounds__(256, 2)
void gemm_gateup(const unsigned short* __restrict__ xb, const unsigned short* __restrict__ wgT,
                 const unsigned short* __restrict__ wuT, const int* __restrict__ list_tok,
                 const int* __restrict__ tile_e, const int* __restrict__ tile_base,
                 const int* __restrict__ ntiles, unsigned short* __restrict__ hbuf) {
    int tile = blockIdx.x;
    if (tile >= ntiles[0]) return;
    int e = tile_e[tile], base = tile_base[tile], nt = blockIdx.y;

    __shared__ unsigned short As[128 * 64];
    __shared__ unsigned short Bgs[128 * 64];
    __shared__ unsigned short Bus[128 * 64];
    __shared__ int toks[128];

    int tid = threadIdx.x;
    if (tid < 128) toks[tid] = list_tok[base + tid];
    __syncthreads();

    const unsigned short* wg = wgT + ((size_t)e * I_DIM + (size_t)nt * 128) * H_DIM;
    const unsigned short* wu = wuT + ((size_t)e * I_DIM + (size_t)nt * 128) * H_DIM;

    int wv = tid >> 6, lane = tid & 63;
    int sr = lane >> 3;           // row within 1KB staging instr (0..7)
    int sc = lane & 7;            // stored chunk position
    int gc = sc ^ sr;             // global chunk (XOR swizzle)

    const unsigned short* ag[4]; const unsigned short* bgg[4]; const unsigned short* bug[4];
    int lb[4];
#pragma unroll
    for (int i = 0; i < 4; i++) {
        int row = wv * 32 + i * 8 + sr;
        ag[i]  = xb + (size_t)toks[row] * H_DIM + gc * 8;
        bgg[i] = wg + (size_t)row * H_DIM + gc * 8;
        bug[i] = wu + (size_t)row * H_DIM + gc * 8;
        lb[i]  = (wv * 32 + i * 8) * 64;
    }

    f32x4 accg[4][4], accu[4][4];
    f32x4 z = {0.f, 0.f, 0.f, 0.f};
#pragma unroll
    for (int i = 0; i < 4; i++)
#pragma unroll
        for (int j = 0; j < 4; j++) { accg[i][j] = z; accu[i][j] = z; }

    int wm = (wv >> 1) * 64, wn = (wv & 1) * 64;
    int l16 = lane & 15, quad = lane >> 4;

    for (int kb = 0; kb < H_DIM; kb += 64) {
#pragma unroll
        for (int i = 0; i < 4; i++) {
            async16(ag[i] + kb, &As[lb[i]]);
            async16(bgg[i] + kb, &Bgs[lb[i]]);
            async16(bug[i] + kb, &Bus[lb[i]]);
        }
        __syncthreads();
#pragma unroll
        for (int ks = 0; ks < 2; ks++) {
            bf16x8 af[4], bg4[4], bu4[4];
#pragma unroll
            for (int i = 0; i < 4; i++) {
                int row = wm + i * 16 + l16;
                int pos = ((ks * 4 + quad) ^ (row & 7)) * 8;
                af[i] = *(const bf16x8*)(&As[row * 64 + pos]);
            }
#pragma unroll
            for (int j = 0; j < 4; j++) {
                int row = wn + j * 16 + l16;
                int pos = ((ks * 4 + quad) ^ (row & 7)) * 8;
                bg4[j] = *(const bf16x8*)(&Bgs[row * 64 + pos]);
                bu4[j] = *(const bf16x8*)(&Bus[row * 64 + pos]);
            }
#pragma unroll
            for (int i = 0; i < 4; i++)
#pragma unroll
                for (int j = 0; j < 4; j++) {
                    accg[i][j] = __builtin_amdgcn_mfma_f32_16x16x32_bf16(af[i], bg4[j], accg[i][j], 0, 0, 0);
                    accu[i][j] = __builtin_amdgcn_mfma_f32_16x16x32_bf16(af[i], bu4[j], accu[i][j], 0, 0, 0);
                }
        }
        __syncthreads();
    }
#pragma unroll
    for (int i = 0; i < 4; i++) {
#pragma unroll
        for (int r = 0; r < 4; r++) {
            int row = wm + i * 16 + quad * 4 + r;     // C/D: col=lane&15, row=quad*4+reg
            size_t hb = (size_t)(base + row) * I_DIM + (size_t)nt * 128 + wn;
#pragma unroll
            for (int j = 0; j < 4; j++) {
                float g = accg[i][j][r];
                float u = accu[i][j][r];
                float sig = 1.f / (1.f + __expf(-g));
                hbuf[hb + j * 16 + l16] = f2bf(g * sig * u);
            }
        }
    }
}

// ---------- down GEMM: out[tok] += w * (h @ Wd) via fp32 atomics ----------
__global__ __launch_bounds__(256, 4)
void gemm_down(const unsigned short* __restrict__ hbuf, const unsigned short* __restrict__ wdT,
               const int* __restrict__ list_tok, const float* __restrict__ list_w,
               const int* __restrict__ tile_e, const int* __restrict__ tile_base,
               const int* __restrict__ ntiles, float* __restrict__ out) {
    int tile = blockIdx.x;
    if (tile >= ntiles[0]) return;
    int e = tile_e[tile], base = tile_base[tile], nt = blockIdx.y;

    __shared__ unsigned short As[128 * 64];
    __shared__ unsigned short Bs[128 * 64];
    __shared__ int toks[128];
    __shared__ float wsh[128];

    int tid = threadIdx.x;
    if (tid < 128) { toks[tid] = list_tok[base + tid]; wsh[tid] = list_w[base + tid]; }
    __syncthreads();

    const unsigned short* wd = wdT + ((size_t)e * H_DIM + (size_t)nt * 128) * I_DIM;

    int wv = tid >> 6, lane = tid & 63;
    int sr = lane >> 3, sc = lane & 7, gc = sc ^ sr;

    const unsigned short* ag[4]; const unsigned short* bg[4];
    int lb[4];
#pragma unroll
    for (int i = 0; i < 4; i++) {
        int row = wv * 32 + i * 8 + sr;
        ag[i] = hbuf + (size_t)(base + row) * I_DIM + gc * 8;
        bg[i] = wd + (size_t)row * I_DIM + gc * 8;
        lb[i] = (wv * 32 + i * 8) * 64;
    }

    f32x4 acc[4][4];
    f32x4 z = {0.f, 0.f, 0.f, 0.f};
#pragma unroll
    for (int i = 0; i < 4; i++)
#pragma unroll
        for (int j = 0; j < 4; j++) acc[i][j] = z;

    int wm = (wv >> 1) * 64, wn = (wv & 1) * 64;
    int l16 = lane & 15, quad = lane >> 4;

    for (int kb = 0; kb < I_DIM; kb += 64) {
#pragma unroll
        for (int i = 0; i < 4; i++) {
            async16(ag[i] + kb, &As[lb[i]]);
            async16(bg[i] + kb, &Bs[lb[i]]);
        }
        __syncthreads();
#pragma unroll
        for (int ks = 0; ks < 2; ks++) {
            bf16x8 af[4], bf4[4];
#pragma unroll
            for (int i = 0; i < 4; i++) {
                int row = wm + i * 16 + l16;
                int pos = ((ks * 4 + quad) ^ (row & 7)) * 8;
                af[i] = *(const bf16x8*)(&As[row * 64 + pos]);
            }
#pragma unroll
            for (int j = 0; j < 4; j++) {
                int row = wn + j * 16 + l16;
                int pos = ((ks * 4 + quad) ^ (row & 7)) * 8;
                bf4[j] = *(const bf16x8*)(&Bs[row * 64 + pos]);
            }
#pragma unroll
            for (int i = 0; i < 4; i++)
#pragma unroll
                for (int j = 0; j < 4; j++)
                    acc[i][j] = __builtin_amdgcn_mfma_f32_16x16x32_bf16(af[i], bf4[j], acc[i][j], 0, 0, 0);
        }
        __syncthreads();
    }
#pragma unroll
    for (int i = 0; i < 4; i++) {
#pragma unroll
        for (int r = 0; r < 4; r++) {
            int row = wm + i * 16 + quad * 4 + r;
            float wgt = wsh[row];
            if (wgt != 0.f) {
                float* orow = out + (size_t)toks[row] * H_DIM + (size_t)nt * 128 + wn;
#pragma unroll
                for (int j = 0; j < 4; j++)
                    atomicAdd(&orow[j * 16 + l16], wgt * acc[i][j][r]);
            }
        }
    }
}

extern "C" void kernel_launch(void* const* d_in, const int* in_sizes, int n_in,
                              void* d_out, int out_size, void* d_ws, size_t ws_size,
                              hipStream_t stream) {
    const float* x  = (const float*)d_in[0];
    const float* Wr = (const float*)d_in[1];
    const float* Wg = (const float*)d_in[2];
    const float* Wu = (const float*)d_in[3];
    const float* Wd = (const float*)d_in[4];
    float* out = (float*)d_out;
    char* ws = (char*)d_ws;

    size_t off = 0;
    unsigned short* xb   = (unsigned short*)(ws + off); off += (size_t)T_TOK * H_DIM * 2;
    unsigned short* wgT  = (unsigned short*)(ws + off); off += (size_t)E_NUM * H_DIM * I_DIM * 2;
    unsigned short* wuT  = (unsigned short*)(ws + off); off += (size_t)E_NUM * H_DIM * I_DIM * 2;
    unsigned short* wdT  = (unsigned short*)(ws + off); off += (size_t)E_NUM * H_DIM * I_DIM * 2;
    unsigned short* hbuf = (unsigned short*)(ws + off); off += (size_t)CAP * I_DIM * 2;
    int*   topidx  = (int*)(ws + off);   off += (size_t)T_TOK * 2 * 4;
    float* topw    = (float*)(ws + off); off += (size_t)T_TOK * 2 * 4;
    int*   meta    = (int*)(ws + off);   off += 1024;
    int*   counts  = meta;          // 8
    int*   cursors = meta + 8;      // 8
    int*   padded  = meta + 16;     // 8
    int*   offs    = meta + 24;     // 9
    int*   ntiles  = meta + 33;     // 1
    int*   tile_e  = meta + 64;     // 72
    int*   tile_b  = meta + 136;    // 72
    int*   list_tok = (int*)(ws + off);  off += (size_t)CAP * 4;
    float* list_w   = (float*)(ws + off); off += (size_t)CAP * 4;

    hipMemsetAsync(out, 0, (size_t)out_size * sizeof(float), stream);
    hipMemsetAsync(counts, 0, 64, stream);  // counts + cursors

    router_kernel<<<T_TOK, 256, 0, stream>>>(x, Wr, xb, topidx, topw, counts);
    transpose_cvt<<<dim3(I_DIM / 64, H_DIM / 64, E_NUM), dim3(64, 4), 0, stream>>>(Wg, wgT, H_DIM, I_DIM);
    transpose_cvt<<<dim3(I_DIM / 64, H_DIM / 64, E_NUM), dim3(64, 4), 0, stream>>>(Wu, wuT, H_DIM, I_DIM);
    transpose_cvt<<<dim3(H_DIM / 64, I_DIM / 64, E_NUM), dim3(64, 4), 0, stream>>>(Wd, wdT, I_DIM, H_DIM);
    offsets_kernel<<<1, 1, 0, stream>>>(counts, padded, offs, tile_e, tile_b, ntiles);
    scatter_kernel<<<(T_TOK * 2) / 256, 256, 0, stream>>>(topidx, topw, offs, cursors, list_tok, list_w);
    pad_kernel<<<E_NUM, 128, 0, stream>>>(counts, padded, offs, list_tok, list_w);
    gemm_gateup<<<dim3(MAXTILES, I_DIM / 128), 256, 0, stream>>>(xb, wgT, wuT, list_tok, tile_e, tile_b, ntiles, hbuf);
    gemm_down<<<dim3(MAXTILES, H_DIM / 128), 256, 0, stream>>>(hbuf, wdT, list_tok, list_w, tile_e, tile_b, ntiles, out);
}